// Round 1
// baseline (126.489 us; speedup 1.0000x reference)
//
#include <hip/hip_runtime.h>
#include <hip/hip_bf16.h>

#define NBATCH 4
#define NNODE  20000
#define NF     128
#define NK     16
#define BM     64
#define KDIM   256               // stacked K: [x | nei_mean]
#define NROWS  (NBATCH * NNODE)  // 80000

typedef __attribute__((ext_vector_type(8))) short bf16x8_t;
typedef __attribute__((ext_vector_type(4))) float f32x4_t;

__device__ __forceinline__ unsigned short f2bf(float f) {
  // round-to-nearest-even f32 -> bf16 (inputs are finite; no NaN handling)
  unsigned int u = __float_as_uint(f);
  u += 0x7fffu + ((u >> 16) & 1u);
  return (unsigned short)(u >> 16);
}

// byte offset into a [row][512B] LDS tile, XOR-swizzled to spread the
// 512B-stride column accesses across banks (T2-style; both write & read use it)
__device__ __forceinline__ int swz(int row, int kbyte) {
  return (row << 9) + (kbyte ^ ((row & 31) << 4));
}

__global__ __launch_bounds__(256) void sage_fused_kernel(
    const float* __restrict__ x, const int* __restrict__ adj,
    const float* __restrict__ Wself, const float* __restrict__ bself,
    const float* __restrict__ Wnei, const float* __restrict__ bnei,
    float* __restrict__ out)
{
  // sA[64 rows][256 k] bf16 (swizzled rows of 512B)   = 32 KB
  // sW[128 cols][256 k] bf16 = B^T of stacked weights = 64 KB
  __shared__ __align__(16) unsigned char sA[BM * KDIM * 2];
  __shared__ __align__(16) unsigned char sW[NF * KDIM * 2];

  const int tid  = threadIdx.x;
  const int lane = tid & 63;
  const int wid  = tid >> 6;
  const int row0 = blockIdx.x * BM;

  // ---- stage stacked W^T into LDS as bf16 (k<128: W_self, k>=128: W_nei)
  {
    const int o  = tid & 127;          // output column
    const int fg = (tid >> 7) * 4;     // 0 or 4
    for (int f0 = fg; f0 < NF; f0 += 8) {
      const float s0 = Wself[(f0 + 0) * NF + o];
      const float s1 = Wself[(f0 + 1) * NF + o];
      const float s2 = Wself[(f0 + 2) * NF + o];
      const float s3 = Wself[(f0 + 3) * NF + o];
      unsigned int p0 = (unsigned int)f2bf(s0) | ((unsigned int)f2bf(s1) << 16);
      unsigned int p1 = (unsigned int)f2bf(s2) | ((unsigned int)f2bf(s3) << 16);
      *reinterpret_cast<uint2*>(sW + swz(o, f0 * 2)) = make_uint2(p0, p1);

      const float n0 = Wnei[(f0 + 0) * NF + o];
      const float n1 = Wnei[(f0 + 1) * NF + o];
      const float n2 = Wnei[(f0 + 2) * NF + o];
      const float n3 = Wnei[(f0 + 3) * NF + o];
      unsigned int q0 = (unsigned int)f2bf(n0) | ((unsigned int)f2bf(n1) << 16);
      unsigned int q1 = (unsigned int)f2bf(n2) | ((unsigned int)f2bf(n3) << 16);
      *reinterpret_cast<uint2*>(sW + swz(o, (NF + f0) * 2)) = make_uint2(q0, q1);
    }
  }

  // ---- stage x tile (k = 0..127 of sA)
  {
    const int rsub = tid >> 6;           // 0..3
    const int f0   = (tid & 63) * 2;     // 2 floats per lane
    for (int rr = rsub; rr < BM; rr += 4) {
      const float2 v =
          *reinterpret_cast<const float2*>(x + (size_t)(row0 + rr) * NF + f0);
      const unsigned int p =
          (unsigned int)f2bf(v.x) | ((unsigned int)f2bf(v.y) << 16);
      *reinterpret_cast<unsigned int*>(sA + swz(rr, f0 * 2)) = p;
    }
  }

  // ---- gather + mean of neighbors (k = 128..255 of sA); wave handles 16 rows
  for (int rr = wid * 16; rr < wid * 16 + 16; ++rr) {
    const int gr = row0 + rr;
    const int b  = gr / NNODE;
    const float* xb  = x + (size_t)b * NNODE * NF;
    const int* arow  = adj + (size_t)gr * NK;
    float a0 = 0.f, a1 = 0.f;
#pragma unroll
    for (int k = 0; k < NK; ++k) {
      const int idx = arow[k];
      const float2 v =
          *reinterpret_cast<const float2*>(xb + (size_t)idx * NF + lane * 2);
      a0 += v.x;
      a1 += v.y;
    }
    a0 *= (1.f / 16.f);
    a1 *= (1.f / 16.f);
    const unsigned int p =
        (unsigned int)f2bf(a0) | ((unsigned int)f2bf(a1) << 16);
    *reinterpret_cast<unsigned int*>(sA + swz(rr, (NF + lane * 2) * 2)) = p;
  }

  __syncthreads();

  // ---- MFMA: wave wid computes rows [16*wid, 16*wid+16) x all 128 cols
  const int frow = lane & 15;
  const int kgrp = lane >> 4;

  f32x4_t acc[8];
#pragma unroll
  for (int c = 0; c < 8; ++c) acc[c] = (f32x4_t){0.f, 0.f, 0.f, 0.f};

  bf16x8_t afr[8];
#pragma unroll
  for (int s = 0; s < 8; ++s) {
    const int kb = (s * 32 + kgrp * 8) * 2;
    afr[s] = *reinterpret_cast<const bf16x8_t*>(sA + swz(wid * 16 + frow, kb));
  }
#pragma unroll
  for (int c = 0; c < 8; ++c) {
#pragma unroll
    for (int s = 0; s < 8; ++s) {
      const int kb = (s * 32 + kgrp * 8) * 2;
      const bf16x8_t bfr =
          *reinterpret_cast<const bf16x8_t*>(sW + swz(c * 16 + frow, kb));
      acc[c] = __builtin_amdgcn_mfma_f32_16x16x32_bf16(afr[s], bfr, acc[c], 0, 0, 0);
    }
  }

  // ---- epilogue: bias + relu, C/D layout col=lane&15, row=(lane>>4)*4+reg
#pragma unroll
  for (int c = 0; c < 8; ++c) {
    const int col  = c * 16 + frow;
    const float bias = bself[col] + bnei[col];
#pragma unroll
    for (int j = 0; j < 4; ++j) {
      const int r = wid * 16 + kgrp * 4 + j;
      const float v = acc[c][j] + bias;
      out[(size_t)(row0 + r) * NF + col] = fmaxf(v, 0.f);
    }
  }
}

extern "C" void kernel_launch(void* const* d_in, const int* in_sizes, int n_in,
                              void* d_out, int out_size, void* d_ws, size_t ws_size,
                              hipStream_t stream) {
  const float* x     = (const float*)d_in[0];
  const int*   adj   = (const int*)d_in[1];
  const float* Wself = (const float*)d_in[2];
  const float* bself = (const float*)d_in[3];
  const float* Wnei  = (const float*)d_in[4];
  const float* bnei  = (const float*)d_in[5];
  float* out = (float*)d_out;

  dim3 grid(NROWS / BM);   // 1250
  dim3 block(256);
  hipLaunchKernelGGL(sage_fused_kernel, grid, block, 0, stream,
                     x, adj, Wself, bself, Wnei, bnei, out);
}

// Round 2
// 49.087 us; speedup vs baseline: 2.5768x; 2.5768x over previous
//
#include <hip/hip_runtime.h>
#include <hip/hip_bf16.h>

#define NBATCH 4
#define NNODE  20000
#define NF     128
#define NK     16
#define BM     64
#define NROWS  (NBATCH * NNODE)   // 80000
#define NBLK   (NROWS / BM)       // 1250
#define WTF_BYTES 65536           // 8c x 8s x 64lane x 16B fragment-permuted weights
#define XB16_OFF  WTF_BYTES       // bf16 x starts here in ws (20.48 MB)

typedef __attribute__((ext_vector_type(8))) short bf16x8_t;
typedef __attribute__((ext_vector_type(4))) float f32x4_t;

__device__ __forceinline__ unsigned short f2bf(float f) {
  unsigned int u = __float_as_uint(f);
  u += 0x7fffu + ((u >> 16) & 1u);
  return (unsigned short)(u >> 16);
}

// byte offset into sA: [row][512B], XOR-swizzled (both write & read sides)
__device__ __forceinline__ int swz(int row, int kbyte) {
  return (row << 9) + (kbyte ^ ((row & 31) << 4));
}

// ---------------- prep: x f32->bf16, weights -> fragment-permuted bf16 ----
__global__ __launch_bounds__(256) void sage_prep_kernel(
    const float* __restrict__ x, const float* __restrict__ Wself,
    const float* __restrict__ Wnei, unsigned char* __restrict__ ws)
{
  const int bid = blockIdx.x;
  const int tid = threadIdx.x;
  if (bid < 2048) {
    // convert x: 2.56M float4 chunks -> ushort4 bf16 chunks
    const float4* xv = reinterpret_cast<const float4*>(x);
    uint2* xb = reinterpret_cast<uint2*>(ws + XB16_OFF);
    const int total = NROWS * NF / 4;  // 2,560,000
    for (int c = bid * 256 + tid; c < total; c += 2048 * 256) {
      const float4 v = xv[c];
      uint2 p;
      p.x = (unsigned int)f2bf(v.x) | ((unsigned int)f2bf(v.y) << 16);
      p.y = (unsigned int)f2bf(v.z) | ((unsigned int)f2bf(v.w) << 16);
      xb[c] = p;
    }
  } else {
    // fragment-permuted stacked W^T: ft = (c*8+s)*64 + lane, 16B per ft
    const int ft = (bid - 2048) * 256 + tid;   // 0..4095
    const int c = ft >> 9;
    const int s = (ft >> 6) & 7;
    const int l = ft & 63;
    const int col = c * 16 + (l & 15);
    const int k0 = s * 32 + ((l >> 4) << 3);
    unsigned int w[4];
#pragma unroll
    for (int jj = 0; jj < 4; ++jj) {
      const int ka = k0 + jj * 2, kb = k0 + jj * 2 + 1;
      const float va = (ka < NF) ? Wself[ka * NF + col] : Wnei[(ka - NF) * NF + col];
      const float vb = (kb < NF) ? Wself[kb * NF + col] : Wnei[(kb - NF) * NF + col];
      w[jj] = (unsigned int)f2bf(va) | ((unsigned int)f2bf(vb) << 16);
    }
    *reinterpret_cast<uint4*>(ws + (size_t)ft * 16) = make_uint4(w[0], w[1], w[2], w[3]);
  }
}

// ---------------- fused gather + stacked GEMM ----------------------------
__global__ __launch_bounds__(256) void sage_fused_kernel(
    const unsigned char* __restrict__ ws, const int* __restrict__ adj,
    const float* __restrict__ bself, const float* __restrict__ bnei,
    float* __restrict__ out)
{
  __shared__ __align__(16) unsigned char sA[BM * 512];  // 32 KB

  const int tid  = threadIdx.x;
  const int lane = tid & 63;
  const int wid  = tid >> 6;

  // bijective XCD-chunked swizzle: nwg=1250, q=156, r=2
  const int orig = blockIdx.x;
  const int xcd = orig & 7, i = orig >> 3;
  const int q = NBLK / 8, r = NBLK % 8;
  const int bid = (xcd < r ? xcd * (q + 1) : r * (q + 1) + (xcd - r) * q) + i;
  const int row0 = bid * BM;

  const unsigned char* xb16 = ws + XB16_OFF;

  // ---- stage x tile (k-bytes [0,256) of sA), coalesced 16B chunks
  {
    const int kb = (tid & 15) * 16;
#pragma unroll
    for (int it = 0; it < 4; ++it) {
      const int rr = it * 16 + (tid >> 4);
      const uint4 v = *reinterpret_cast<const uint4*>(
          xb16 + (size_t)(row0 + rr) * 256 + kb);
      *reinterpret_cast<uint4*>(sA + swz(rr, kb)) = v;
    }
  }

  // ---- gather + mean (k-bytes [256,512)); 16 lanes per row, 4 rows/iter
  {
    const int fg = (lane & 15) * 16;  // 16-byte feature chunk (8 bf16)
#pragma unroll
    for (int it = 0; it < 4; ++it) {
      const int rr = wid * 16 + it * 4 + (lane >> 4);
      const int gr = row0 + rr;
      const int b  = gr / NNODE;
      const unsigned char* xbb = xb16 + (size_t)b * NNODE * 256;
      const int4* a4 = reinterpret_cast<const int4*>(adj + (size_t)gr * NK);
      float a0=0,a1=0,a2=0,a3=0,a4f=0,a5=0,a6=0,a7=0;
#pragma unroll
      for (int kk = 0; kk < 4; ++kk) {
        const int4 idx = a4[kk];
        const int id[4] = {idx.x, idx.y, idx.z, idx.w};
#pragma unroll
        for (int m = 0; m < 4; ++m) {
          const uint4 v = *reinterpret_cast<const uint4*>(
              xbb + (size_t)id[m] * 256 + fg);
          a0 += __uint_as_float(v.x << 16);
          a1 += __uint_as_float(v.x & 0xffff0000u);
          a2 += __uint_as_float(v.y << 16);
          a3 += __uint_as_float(v.y & 0xffff0000u);
          a4f += __uint_as_float(v.z << 16);
          a5 += __uint_as_float(v.z & 0xffff0000u);
          a6 += __uint_as_float(v.w << 16);
          a7 += __uint_as_float(v.w & 0xffff0000u);
        }
      }
      const float sc = 1.f / 16.f;
      uint4 p;
      p.x = (unsigned int)f2bf(a0*sc) | ((unsigned int)f2bf(a1*sc) << 16);
      p.y = (unsigned int)f2bf(a2*sc) | ((unsigned int)f2bf(a3*sc) << 16);
      p.z = (unsigned int)f2bf(a4f*sc) | ((unsigned int)f2bf(a5*sc) << 16);
      p.w = (unsigned int)f2bf(a6*sc) | ((unsigned int)f2bf(a7*sc) << 16);
      *reinterpret_cast<uint4*>(sA + swz(rr, 256 + fg)) = p;
    }
  }

  __syncthreads();

  // ---- MFMA: wave wid -> rows [16*wid,16*wid+16) x 128 cols
  const int frow = lane & 15;
  const int kgrp = lane >> 4;

  f32x4_t acc[8];
#pragma unroll
  for (int c = 0; c < 8; ++c) acc[c] = (f32x4_t){0.f, 0.f, 0.f, 0.f};

  bf16x8_t afr[8];
#pragma unroll
  for (int s = 0; s < 8; ++s) {
    const int kb = s * 64 + kgrp * 16;
    afr[s] = *reinterpret_cast<const bf16x8_t*>(sA + swz(wid * 16 + frow, kb));
  }

  const bf16x8_t* wtf = reinterpret_cast<const bf16x8_t*>(ws);
#pragma unroll
  for (int c = 0; c < 8; ++c) {
#pragma unroll
    for (int s = 0; s < 8; ++s) {
      const bf16x8_t bfr = wtf[(c * 8 + s) * 64 + lane];
      acc[c] = __builtin_amdgcn_mfma_f32_16x16x32_bf16(afr[s], bfr, acc[c], 0, 0, 0);
    }
  }

  // ---- epilogue: bias + relu; C/D: col=lane&15, row=(lane>>4)*4+reg
#pragma unroll
  for (int c = 0; c < 8; ++c) {
    const int col  = c * 16 + frow;
    const float bias = bself[col] + bnei[col];
#pragma unroll
    for (int j = 0; j < 4; ++j) {
      const int rr = wid * 16 + kgrp * 4 + j;
      const float v = acc[c][j] + bias;
      out[(size_t)(row0 + rr) * NF + col] = fmaxf(v, 0.f);
    }
  }
}

extern "C" void kernel_launch(void* const* d_in, const int* in_sizes, int n_in,
                              void* d_out, int out_size, void* d_ws, size_t ws_size,
                              hipStream_t stream) {
  const float* x     = (const float*)d_in[0];
  const int*   adj   = (const int*)d_in[1];
  const float* Wself = (const float*)d_in[2];
  const float* bself = (const float*)d_in[3];
  const float* Wnei  = (const float*)d_in[4];
  const float* bnei  = (const float*)d_in[5];
  float* out = (float*)d_out;
  unsigned char* ws = (unsigned char*)d_ws;

  hipLaunchKernelGGL(sage_prep_kernel, dim3(2064), dim3(256), 0, stream,
                     x, Wself, Wnei, ws);
  hipLaunchKernelGGL(sage_fused_kernel, dim3(NBLK), dim3(256), 0, stream,
                     ws, adj, bself, bnei, out);
}